// Round 1
// baseline (127.056 us; speedup 1.0000x reference)
//
#include <hip/hip_runtime.h>

// Integer-LIF recurrence over T=16 time steps.
// x: (T, B, C, H, W) fp32, out: same shape fp32.
// Per spatial element: h_t = (v_{t-1} - s_{t-1})*0.25 + x_t;
//                      s_t = floor(clip(h_t, 0, 4) + 0.5); carry (h_t, s_t).
// Purely memory-bound: 268 MB in + 268 MB out, no reuse.

#define T_STEPS 16
#define N_SPATIAL (32LL * 128 * 32 * 32)   // B*C*H*W = 4,194,304
#define N4 (N_SPATIAL / 4)                 // float4 elements per time plane

__device__ __forceinline__ float lif_step(float xt, float& v, float& s) {
    float h = (v - s) * 0.25f + xt;                       // mul by 0.25 is exact
    float c = fminf(fmaxf(h, 0.0f), 4.0f);
    float sp = floorf(c + 0.5f);
    v = h;
    s = sp;
    return sp;
}

__global__ void __launch_bounds__(256)
ILIFNode_25838523253095_kernel(const float4* __restrict__ x,
                               float4* __restrict__ out) {
    long long i = (long long)blockIdx.x * blockDim.x + threadIdx.x;
    if (i >= N4) return;

    float4 v = make_float4(0.f, 0.f, 0.f, 0.f);
    float4 s = make_float4(0.f, 0.f, 0.f, 0.f);

#pragma unroll
    for (int t = 0; t < T_STEPS; ++t) {
        float4 xt = x[(long long)t * N4 + i];
        float4 sp;
        sp.x = lif_step(xt.x, v.x, s.x);
        sp.y = lif_step(xt.y, v.y, s.y);
        sp.z = lif_step(xt.z, v.z, s.z);
        sp.w = lif_step(xt.w, v.w, s.w);
        out[(long long)t * N4 + i] = sp;
    }
}

extern "C" void kernel_launch(void* const* d_in, const int* in_sizes, int n_in,
                              void* d_out, int out_size, void* d_ws, size_t ws_size,
                              hipStream_t stream) {
    const float4* x = (const float4*)d_in[0];
    float4* out = (float4*)d_out;
    const long long n4 = N4;               // 1,048,576 threads
    const int block = 256;
    const int grid = (int)((n4 + block - 1) / block);   // 4096 blocks
    ILIFNode_25838523253095_kernel<<<grid, block, 0, stream>>>(x, out);
}

// Round 5
// 94.319 us; speedup vs baseline: 1.3471x; 1.3471x over previous
//
#include <hip/hip_runtime.h>

// Integer-LIF recurrence over T=16 time steps.
// x: (T, B, C, H, W) fp32, out: same shape fp32.
// Per element: h_t = (v-s)*0.25 + x_t; s_t = floor(clip(h_t,0,4)+0.5).
// Memory-bound streaming op. Round-1 lesson: tight load->wait->store loop
// serializes on vmcnt; fix with 2-deep software pipeline x 2 streams/thread
// + nontemporal stores (keep input resident in 256MB LLC across replays).
// Round-3 fix: __builtin_nontemporal_store needs a clang ext_vector type,
// not HIP's float4 struct.

#define T_STEPS 16
#define N_SPATIAL (32LL * 128 * 32 * 32)   // B*C*H*W = 4,194,304
#define N4 ((int)(N_SPATIAL / 4))          // 1,048,576 float4 per time plane
#define HALF (N4 / 2)                      // 524,288: two streams per thread

typedef float f32x4 __attribute__((ext_vector_type(4)));

__device__ __forceinline__ f32x4 lif_step4(f32x4 xt, f32x4& v, f32x4& s) {
    f32x4 sp;
#pragma unroll
    for (int c = 0; c < 4; ++c) {
        float h = (v[c] - s[c]) * 0.25f + xt[c];   // *0.25 exact (pow2)
        float cl = fminf(fmaxf(h, 0.0f), 4.0f);
        float p = floorf(cl + 0.5f);
        sp[c] = p;
        v[c] = h;
        s[c] = p;
    }
    return sp;
}

__global__ void __launch_bounds__(256)
ILIFNode_25838523253095_kernel(const f32x4* __restrict__ x,
                               f32x4* __restrict__ out) {
    int i = blockIdx.x * blockDim.x + threadIdx.x;   // stream A index
    if (i >= HALF) return;
    int j = i + HALF;                                // stream B index

    f32x4 zero = {0.f, 0.f, 0.f, 0.f};
    f32x4 va = zero, sa = zero, vb = zero, sb = zero;

    // 2-deep prefetch pipeline: t and t+1 in flight for both streams.
    f32x4 a0 = x[0 * N4 + i];
    f32x4 b0 = x[0 * N4 + j];
    f32x4 a1 = x[1 * N4 + i];
    f32x4 b1 = x[1 * N4 + j];

#pragma unroll
    for (int t = 0; t < T_STEPS; ++t) {
        f32x4 a2 = zero, b2 = zero;
        if (t + 2 < T_STEPS) {
            a2 = x[(t + 2) * N4 + i];
            b2 = x[(t + 2) * N4 + j];
        }
        f32x4 spa = lif_step4(a0, va, sa);
        f32x4 spb = lif_step4(b0, vb, sb);
        __builtin_nontemporal_store(spa, &out[t * N4 + i]);
        __builtin_nontemporal_store(spb, &out[t * N4 + j]);
        a0 = a1; a1 = a2;
        b0 = b1; b1 = b2;
    }
}

extern "C" void kernel_launch(void* const* d_in, const int* in_sizes, int n_in,
                              void* d_out, int out_size, void* d_ws, size_t ws_size,
                              hipStream_t stream) {
    const f32x4* x = (const f32x4*)d_in[0];
    f32x4* out = (f32x4*)d_out;
    const int block = 256;
    const int grid = (HALF + block - 1) / block;     // 2048 blocks
    ILIFNode_25838523253095_kernel<<<grid, block, 0, stream>>>(x, out);
}

// Round 6
// 94.066 us; speedup vs baseline: 1.3507x; 1.0027x over previous
//
#include <hip/hip_runtime.h>

// Integer-LIF recurrence over T=16 time steps.
// x: (T, B, C, H, W) fp32, out: same shape fp32.
// Per element: h_t = (v-s)*0.25 + x_t; s_t = floor(clip(h_t,0,4)+0.5).
// Memory-bound streaming op. HBM traffic floor: 268MB write + ~134MB HBM read
// (L3 serves the other half of the input). Round-5: 94.3us @ 5.7 TB/s combined.
// Round-5 lesson: VGPR=28 proves the compiler sank my "2-deep pipeline" loads
// back to their uses. This round: explicit 4-deep prefetch over statically
// indexed buf[16] arrays (full unroll), targeting VGPR~60 (still 32 waves/CU).

#define T_STEPS 16
#define N_SPATIAL (32LL * 128 * 32 * 32)   // B*C*H*W = 4,194,304
#define N4 ((int)(N_SPATIAL / 4))          // 1,048,576 float4 per time plane
#define HALF (N4 / 2)                      // 524,288: two streams per thread
#define PF 4                               // prefetch depth (time steps ahead)

typedef float f32x4 __attribute__((ext_vector_type(4)));

__device__ __forceinline__ f32x4 lif_step4(f32x4 xt, f32x4& v, f32x4& s) {
    f32x4 sp;
#pragma unroll
    for (int c = 0; c < 4; ++c) {
        float h = (v[c] - s[c]) * 0.25f + xt[c];   // *0.25 exact (pow2)
        float cl = fminf(fmaxf(h, 0.0f), 4.0f);
        float p = floorf(cl + 0.5f);
        sp[c] = p;
        v[c] = h;
        s[c] = p;
    }
    return sp;
}

__global__ void __launch_bounds__(256)
ILIFNode_25838523253095_kernel(const f32x4* __restrict__ x,
                               f32x4* __restrict__ out) {
    int i = blockIdx.x * blockDim.x + threadIdx.x;   // stream A index
    if (i >= HALF) return;
    int j = i + HALF;                                // stream B index

    f32x4 zero = {0.f, 0.f, 0.f, 0.f};
    f32x4 va = zero, sa = zero, vb = zero, sb = zero;

    // Statically-indexed buffers; only PF entries live at any point.
    f32x4 bufA[T_STEPS], bufB[T_STEPS];

    // Prologue: issue PF loads per stream before any compute.
#pragma unroll
    for (int t = 0; t < PF; ++t) {
        bufA[t] = x[t * N4 + i];
        bufB[t] = x[t * N4 + j];
    }

#pragma unroll
    for (int t = 0; t < T_STEPS; ++t) {
        // Issue the t+PF loads before consuming buf[t] so the compiler
        // keeps PF loads in flight (waits become partial, not drains).
        if (t + PF < T_STEPS) {
            bufA[t + PF] = x[(t + PF) * N4 + i];
            bufB[t + PF] = x[(t + PF) * N4 + j];
        }
        f32x4 spa = lif_step4(bufA[t], va, sa);
        f32x4 spb = lif_step4(bufB[t], vb, sb);
        __builtin_nontemporal_store(spa, &out[t * N4 + i]);
        __builtin_nontemporal_store(spb, &out[t * N4 + j]);
    }
}

extern "C" void kernel_launch(void* const* d_in, const int* in_sizes, int n_in,
                              void* d_out, int out_size, void* d_ws, size_t ws_size,
                              hipStream_t stream) {
    const f32x4* x = (const f32x4*)d_in[0];
    f32x4* out = (f32x4*)d_out;
    const int block = 256;
    const int grid = (HALF + block - 1) / block;     // 2048 blocks, 8192 waves
    ILIFNode_25838523253095_kernel<<<grid, block, 0, stream>>>(x, out);
}

// Round 9
// 92.982 us; speedup vs baseline: 1.3665x; 1.0117x over previous
//
#include <hip/hip_runtime.h>

// Integer-LIF recurrence over T=16 time steps.
// x: (T, B, C, H, W) fp32, out: same shape fp32.
// Per element: h_t = (v-s)*0.25 + x_t; s_t = floor(clip(h_t,0,4)+0.5).
// Memory-bound streaming. R5/R6: 94us @ 5.7 TB/s combined; FETCH pinned at
// 134MB (write stream evicts half the input from the 256MB LLC).
// R8 lesson: inline-asm global_store corrupted data (absmax=4.5 = cl+0.5
// intermediate): compiler can't see the store's pending async read of its
// source VGPRs and reused them. Fix: compiler-visible buffer-store intrinsic
// with CPol aux bits SC0|NT|SC1 = 0x13 (write-through, no-allocate) so
// register hazards are tracked by the compiler.

#define T_STEPS 16
#define N_SPATIAL (32LL * 128 * 32 * 32)   // B*C*H*W = 4,194,304
#define N4 ((int)(N_SPATIAL / 4))          // 1,048,576 float4 per time plane
#define HALF (N4 / 2)                      // 524,288: two streams per thread
#define PF 4                               // prefetch depth (time steps ahead)

typedef float f32x4 __attribute__((ext_vector_type(4)));
typedef int   i32x4 __attribute__((ext_vector_type(4)));

#if defined(__has_builtin)
#  if __has_builtin(__builtin_amdgcn_make_buffer_rsrc) && \
      __has_builtin(__builtin_amdgcn_raw_ptr_buffer_store_b128)
#    define USE_BUFFER_STORE 1
#  else
#    define USE_BUFFER_STORE 0
#  endif
#else
#  define USE_BUFFER_STORE 0
#endif

__device__ __forceinline__ f32x4 lif_step4(f32x4 xt, f32x4& v, f32x4& s) {
    f32x4 sp;
#pragma unroll
    for (int c = 0; c < 4; ++c) {
        float h = (v[c] - s[c]) * 0.25f + xt[c];   // *0.25 exact (pow2)
        float cl = fminf(fmaxf(h, 0.0f), 4.0f);
        float p = floorf(cl + 0.5f);
        sp[c] = p;
        v[c] = h;
        s[c] = p;
    }
    return sp;
}

__global__ void __launch_bounds__(256, 4)
ILIFNode_25838523253095_kernel(const f32x4* __restrict__ x,
                               f32x4* __restrict__ out) {
    int i = blockIdx.x * blockDim.x + threadIdx.x;   // stream A index
    if (i >= HALF) return;
    int j = i + HALF;                                // stream B index

#if USE_BUFFER_STORE
    // SRD over the whole output; num_records=-1 disables bounds check.
    __amdgpu_buffer_rsrc_t rsrc = __builtin_amdgcn_make_buffer_rsrc(
        (void*)out, (short)0, -1, 0x00020000);
#endif

    f32x4 zero = {0.f, 0.f, 0.f, 0.f};
    f32x4 va = zero, sa = zero, vb = zero, sb = zero;

    // Statically-indexed buffers; only PF entries live at any point.
    f32x4 bufA[T_STEPS], bufB[T_STEPS];

#pragma unroll
    for (int t = 0; t < PF; ++t) {
        bufA[t] = x[t * N4 + i];
        bufB[t] = x[t * N4 + j];
    }

#pragma unroll
    for (int t = 0; t < T_STEPS; ++t) {
        if (t + PF < T_STEPS) {
            bufA[t + PF] = x[(t + PF) * N4 + i];
            bufB[t + PF] = x[(t + PF) * N4 + j];
        }
        f32x4 spa = lif_step4(bufA[t], va, sa);
        f32x4 spb = lif_step4(bufB[t], vb, sb);
#if USE_BUFFER_STORE
        // aux=0x13: SC0(1) | NT(2) | SC1(16) -> streaming, no-allocate.
        __builtin_amdgcn_raw_ptr_buffer_store_b128(
            __builtin_bit_cast(i32x4, spa), rsrc, (t * N4 + i) * 16, 0, 0x13);
        __builtin_amdgcn_raw_ptr_buffer_store_b128(
            __builtin_bit_cast(i32x4, spb), rsrc, (t * N4 + j) * 16, 0, 0x13);
#else
        __builtin_nontemporal_store(spa, &out[t * N4 + i]);
        __builtin_nontemporal_store(spb, &out[t * N4 + j]);
#endif
    }
}

extern "C" void kernel_launch(void* const* d_in, const int* in_sizes, int n_in,
                              void* d_out, int out_size, void* d_ws, size_t ws_size,
                              hipStream_t stream) {
    const f32x4* x = (const f32x4*)d_in[0];
    f32x4* out = (f32x4*)d_out;
    const int block = 256;
    const int grid = (HALF + block - 1) / block;     // 2048 blocks, 8192 waves
    ILIFNode_25838523253095_kernel<<<grid, block, 0, stream>>>(x, out);
}